// Round 4
// baseline (196.003 us; speedup 1.0000x reference)
//
#include <hip/hip_runtime.h>
#include <cstddef>

// B,N,C,H = 2,2048,768,12; HD=64.  bf16 MFMA everywhere, fp32 accum.
typedef __attribute__((ext_vector_type(8))) short bf16x8;
typedef __attribute__((ext_vector_type(4))) float f32x4;

constexpr int Bb = 2, Nn = 2048, Cc = 768, Hh = 12, HDd = 64;
// 0.125 (HD^-1/2) * log2(e): softmax via exp2, mul folded into Q.
constexpr float QSCALE = 0.125f * 1.44269504088896340736f;

__device__ inline short f2bf(float f) {
  unsigned u = __builtin_bit_cast(unsigned, f);
  u += 0x7fff + ((u >> 16) & 1);  // RNE
  return (short)(u >> 16);
}
// pack two f32 -> {bf16(a) lo, bf16(b) hi} in one VALU op
__device__ inline unsigned cvtpk(float a, float b) {
  unsigned r;
  asm("v_cvt_pk_bf16_f32 %0, %1, %2" : "=v"(r) : "v"(a), "v"(b));
  return r;
}
// async global->LDS, 16B/lane; dest wave-uniform base + lane*16 (linear).
__device__ inline void gl_lds16(const void* g, void* l) {
  __builtin_amdgcn_global_load_lds(
      (const __attribute__((address_space(1))) unsigned*)g,
      (__attribute__((address_space(3))) unsigned*)l, 16, 0, 0);
}
__device__ inline bf16x8 lds8(const short* p) { return *(const bf16x8*)p; }
__device__ inline bf16x8 ld_frag(const short* base, int row, int ch) {
  return *(const bf16x8*)&base[row * 64 + (((ch ^ (row & 7)) << 3))];
}

// ---------------------------------------------------------------------------
// f32 -> bf16 convert
// ---------------------------------------------------------------------------
__global__ __launch_bounds__(256) void cvt_kernel(const float* __restrict__ s,
                                                  short* __restrict__ d) {
  const int i = (blockIdx.x * 256 + threadIdx.x) * 4;
  const float4 v = *(const float4*)&s[i];
  short4 o;
  o.x = f2bf(v.x); o.y = f2bf(v.y); o.z = f2bf(v.z); o.w = f2bf(v.w);
  *(short4*)&d[i] = o;
}

// ---------------------------------------------------------------------------
// QKV GEMM: scatter into Q (pre-scaled by QSCALE), K (B,H,N,64) and
// V transposed (B,H,64,N).  128x128 tile, BK=64, 4 waves.
// ---------------------------------------------------------------------------
__global__ __launch_bounds__(256) void qkv_mfma(
    const short* __restrict__ A, const short* __restrict__ W,
    short* __restrict__ Qg, short* __restrict__ Kg, short* __restrict__ Vtg) {
  __shared__ short As[128 * 64];
  __shared__ short Bs[128 * 64];
  const int t = threadIdx.x, l = t & 63, w = t >> 6;
  const int lr = l & 15, lh = l >> 4;
  const int m0 = blockIdx.x * 128, r0 = blockIdx.y * 128;
  const int wr = w >> 1, wc = w & 1;
  f32x4 acc[4][4];
#pragma unroll
  for (int i = 0; i < 4; ++i)
#pragma unroll
    for (int j = 0; j < 4; ++j) acc[i][j] = (f32x4){0.f, 0.f, 0.f, 0.f};

  for (int k0 = 0; k0 < Cc; k0 += 64) {
    __syncthreads();
#pragma unroll
    for (int u = 0; u < 4; ++u) {
      const int du = (w * 4 + u) * 64 + l;
      const int row = du >> 3, ch = du & 7, sch = ch ^ (row & 7);
      gl_lds16(A + (size_t)(m0 + row) * Cc + k0 + sch * 8,
               &As[(w * 4 + u) * 512]);
      gl_lds16(W + (size_t)(r0 + row) * Cc + k0 + sch * 8,
               &Bs[(w * 4 + u) * 512]);
    }
    __syncthreads();
#pragma unroll
    for (int kp = 0; kp < 2; ++kp) {
      bf16x8 af[4], bfv[4];
#pragma unroll
      for (int i = 0; i < 4; ++i)
        af[i] = ld_frag(As, wr * 64 + i * 16 + lr, kp * 4 + lh);
#pragma unroll
      for (int j = 0; j < 4; ++j)
        bfv[j] = ld_frag(Bs, wc * 64 + j * 16 + lr, kp * 4 + lh);
#pragma unroll
      for (int i = 0; i < 4; ++i)
#pragma unroll
        for (int j = 0; j < 4; ++j)
          acc[i][j] = __builtin_amdgcn_mfma_f32_16x16x32_bf16(
              af[i], bfv[j], acc[i][j], 0, 0, 0);
    }
  }
  const int which = r0 / Cc;  // 128 | 768: block-uniform
  const int rbase = r0 % Cc;
  const int bq = m0 >> 11;
  const int nb = (m0 & 2047) + wr * 64;
  if (which == 2) {  // V: transposed layout -> short4 stores along n
#pragma unroll
    for (int j = 0; j < 4; ++j) {
      const int rr = rbase + wc * 64 + j * 16 + lr;
      const int head = rr >> 6, dd = rr & 63;
      short* vp = &Vtg[(((size_t)bq * Hh + head) * HDd + dd) * Nn];
#pragma unroll
      for (int i = 0; i < 4; ++i) {
        short4 o;
        o.x = f2bf(acc[i][j][0]); o.y = f2bf(acc[i][j][1]);
        o.z = f2bf(acc[i][j][2]); o.w = f2bf(acc[i][j][3]);
        *(short4*)&vp[nb + i * 16 + lh * 4] = o;
      }
    }
  } else {
    const float scl = (which == 0) ? QSCALE : 1.0f;
    short* __restrict__ dst = (which == 0) ? Qg : Kg;
#pragma unroll
    for (int j = 0; j < 4; ++j) {
      const int rr = rbase + wc * 64 + j * 16 + lr;
      const int head = rr >> 6, dd = rr & 63;
      short* dp = &dst[((size_t)bq * Hh + head) * Nn * HDd + dd];
#pragma unroll
      for (int i = 0; i < 4; ++i)
#pragma unroll
        for (int r = 0; r < 4; ++r)
          dp[(size_t)(nb + i * 16 + lh * 4 + r) * HDd] =
              f2bf(acc[i][j][r] * scl);
    }
  }
}

// ---------------------------------------------------------------------------
// Attention pass 1.  128 threads = 2 waves; block q-tile 64, each wave 32 q.
// Q in regs (2 kp x 2 qi frags); K/V double-buffered in LDS; P per-wave in
// LDS; row-sum L via mfma(P, ones) -> lane-local normalization (no shuffles).
// ---------------------------------------------------------------------------
__global__ __launch_bounds__(128, 2) void attn_pass1(
    const short* __restrict__ Qg, const short* __restrict__ Kg,
    const short* __restrict__ Vtg, float* __restrict__ Linv,
    short* __restrict__ OHb) {
  // shorts: [buf0: K 4096 | V 4096][buf1: K 4096 | V 4096][P: 2 x 2048]
  __shared__ short SM[2 * 8192 + 2 * 2048];
  const int t = threadIdx.x, l = t & 63, w = t >> 6;
  const int lr = l & 15, lh = l >> 4;
  // XCD-chunked swizzle (768 % 8 == 0)
  const int bid0 = blockIdx.x;
  const int bid = (bid0 & 7) * 96 + (bid0 >> 3);
  const int q0 = (bid & 31) * 64;
  const int head = (bid >> 5) % Hh;
  const int b = bid / (32 * Hh);
  const size_t base = (size_t)b * Hh + head;
  const short* Qh = Qg + base * Nn * HDd;
  const short* Kh = Kg + base * Nn * HDd;
  const short* Vh = Vtg + base * HDd * Nn;
  const int qw = q0 + w * 32;
  const int PB = 16384 + w * 2048;

  const bf16x8 onesf = {0x3F80, 0x3F80, 0x3F80, 0x3F80,
                        0x3F80, 0x3F80, 0x3F80, 0x3F80};

  // hoisted LDS short-offsets
  int fof[2][4], pof[2][2], wof[2][4];
#pragma unroll
  for (int kp = 0; kp < 2; ++kp)
#pragma unroll
    for (int i = 0; i < 4; ++i)
      fof[kp][i] = (i * 16 + lr) * 64 + (((kp * 4 + lh) ^ (lr & 7)) << 3);
#pragma unroll
  for (int qi = 0; qi < 2; ++qi) {
#pragma unroll
    for (int kp = 0; kp < 2; ++kp)
      pof[qi][kp] =
          (qi * 16 + lr) * 64 + (((kp * 4 + lh) ^ (lr & 7)) << 3);
#pragma unroll
    for (int i = 0; i < 4; ++i) {
      const int ch = 2 * i + (lh >> 1);
      wof[qi][i] =
          (qi * 16 + lr) * 64 + ((ch ^ (lr & 7)) << 3) + (lh & 1) * 4;
    }
  }

  bf16x8 qf[2][2];
#pragma unroll
  for (int kp = 0; kp < 2; ++kp)
#pragma unroll
    for (int qi = 0; qi < 2; ++qi)
      qf[kp][qi] = *(const bf16x8*)&Qh[(size_t)(qw + qi * 16 + lr) * HDd +
                                       kp * 32 + lh * 8];

  f32x4 accO[2][4], accL[2];
#pragma unroll
  for (int qi = 0; qi < 2; ++qi) {
    accL[qi] = (f32x4){0.f, 0.f, 0.f, 0.f};
#pragma unroll
    for (int j = 0; j < 4; ++j) accO[qi][j] = (f32x4){0.f, 0.f, 0.f, 0.f};
  }

  auto stage = [&](const int buf, const int tile) {
    const short* Kt = Kh + (size_t)tile * (64 * HDd);
    const short* Vt = Vh + tile * 64;
#pragma unroll
    for (int u = 0; u < 4; ++u) {
      const int du = (u * 2 + w) * 64 + l;
      const int row = du >> 3, ch = du & 7, sch = ch ^ (row & 7);
      gl_lds16(Kt + row * 64 + sch * 8, &SM[buf * 8192 + (u * 2 + w) * 512]);
      gl_lds16(Vt + (size_t)row * Nn + sch * 8,
               &SM[buf * 8192 + 4096 + (u * 2 + w) * 512]);
    }
  };

  auto compute = [&](const int kb) {
    f32x4 sacc[4][2];
#pragma unroll
    for (int i = 0; i < 4; ++i)
#pragma unroll
      for (int qi = 0; qi < 2; ++qi) sacc[i][qi] = (f32x4){0.f, 0.f, 0.f, 0.f};
    __builtin_amdgcn_s_setprio(1);
#pragma unroll
    for (int kp = 0; kp < 2; ++kp)
#pragma unroll
      for (int i = 0; i < 4; ++i) {
        const bf16x8 kf = lds8(&SM[kb + fof[kp][i]]);
#pragma unroll
        for (int qi = 0; qi < 2; ++qi)
          sacc[i][qi] = __builtin_amdgcn_mfma_f32_16x16x32_bf16(
              kf, qf[kp][qi], sacc[i][qi], 0, 0, 0);
      }
    __builtin_amdgcn_s_setprio(0);
#pragma unroll
    for (int i = 0; i < 4; ++i)
#pragma unroll
      for (int qi = 0; qi < 2; ++qi) {
        const float p0 = exp2f(sacc[i][qi][0]), p1 = exp2f(sacc[i][qi][1]);
        const float p2 = exp2f(sacc[i][qi][2]), p3 = exp2f(sacc[i][qi][3]);
        uint2 pk;
        pk.x = cvtpk(p0, p1);
        pk.y = cvtpk(p2, p3);
        *(uint2*)&SM[PB + wof[qi][i]] = pk;
      }
    __builtin_amdgcn_s_setprio(1);
#pragma unroll
    for (int kp = 0; kp < 2; ++kp)
#pragma unroll
      for (int qi = 0; qi < 2; ++qi) {
        const bf16x8 pa = lds8(&SM[PB + pof[qi][kp]]);
        accL[qi] = __builtin_amdgcn_mfma_f32_16x16x32_bf16(pa, onesf, accL[qi],
                                                           0, 0, 0);
#pragma unroll
        for (int j = 0; j < 4; ++j)
          accO[qi][j] = __builtin_amdgcn_mfma_f32_16x16x32_bf16(
              pa, lds8(&SM[kb + 4096 + fof[kp][j]]), accO[qi][j], 0, 0, 0);
      }
    __builtin_amdgcn_s_setprio(0);
  };

  stage(0, 0);
  __syncthreads();
#pragma unroll 1
  for (int it = 0; it < Nn / 64; it += 2) {
    stage(1, it + 1);
    compute(0);
    __syncthreads();
    if (it + 2 < Nn / 64) stage(0, it + 2);
    compute(8192);
    __syncthreads();
  }

#pragma unroll
  for (int qi = 0; qi < 2; ++qi) {
    f32x4 linvq;
#pragma unroll
    for (int r = 0; r < 4; ++r) linvq[r] = 1.0f / accL[qi][r];
    if (lr == 0)
      *(f32x4*)&Linv[base * Nn + qw + qi * 16 + 4 * lh] = linvq;
#pragma unroll
    for (int j = 0; j < 4; ++j)
#pragma unroll
      for (int r = 0; r < 4; ++r)
        OHb[((size_t)b * Nn + qw + qi * 16 + 4 * lh + r) * Cc + head * HDd +
            j * 16 + lr] = f2bf(accO[qi][j][r] * linvq[r]);
  }
}

// ---------------------------------------------------------------------------
// Score: score[b][q][kv] = (1/H) sum_h 2^(qk) * Linv.  Block: 64 kv x 128 q,
// 4 waves x 32 q.  K double-buffered in LDS; Q frags + Linv direct from
// global (next head prefetched into regs).  Grid 1024, XCD-chunked.
// ---------------------------------------------------------------------------
__global__ __launch_bounds__(256, 4) void score_mfma(
    const short* __restrict__ Qg, const short* __restrict__ Kg,
    const float* __restrict__ Linv, float* __restrict__ score) {
  __shared__ short SM[2 * 4096];  // K dbuf, 8KB each
  const int t = threadIdx.x, l = t & 63, w = t >> 6;
  const int lr = l & 15, lh = l >> 4;
  // swizzle: each XCD gets 4 q-tiles(128) x all kv for one b
  const int raw = blockIdx.x;
  const int nid = (raw & 7) * 128 + (raw >> 3);
  const int kv0 = (nid & 31) * 64;
  const int q0 = ((nid >> 5) & 15) * 128;
  const int b = nid >> 9;
  const int qw = q0 + w * 32;

  int fof[2][4];
#pragma unroll
  for (int kp = 0; kp < 2; ++kp)
#pragma unroll
    for (int i = 0; i < 4; ++i)
      fof[kp][i] = (i * 16 + lr) * 64 + (((kp * 4 + lh) ^ (lr & 7)) << 3);

  f32x4 sc[4][2];
#pragma unroll
  for (int i = 0; i < 4; ++i)
#pragma unroll
    for (int qi = 0; qi < 2; ++qi) sc[i][qi] = (f32x4){0.f, 0.f, 0.f, 0.f};

  auto stage = [&](const int buf, const int h) {
    const short* Kt = Kg + (((size_t)b * Hh + h) * Nn + kv0) * HDd;
#pragma unroll
    for (int u = 0; u < 2; ++u) {
      const int du = (u * 4 + w) * 64 + l;
      const int row = du >> 3, ch = du & 7, sch = ch ^ (row & 7);
      gl_lds16(Kt + row * 64 + sch * 8, &SM[buf * 4096 + (u * 4 + w) * 512]);
    }
  };
  auto ldq = [&](bf16x8 qf[2][2], f32x4 lv[2], const int h) {
    const size_t hb = (size_t)b * Hh + h;
#pragma unroll
    for (int kp = 0; kp < 2; ++kp)
#pragma unroll
      for (int qi = 0; qi < 2; ++qi)
        qf[kp][qi] = *(const bf16x8*)&Qg[(hb * Nn + qw + qi * 16 + lr) * HDd +
                                         kp * 32 + lh * 8];
#pragma unroll
    for (int qi = 0; qi < 2; ++qi)
      lv[qi] = *(const f32x4*)&Linv[hb * Nn + qw + qi * 16 + 4 * lh];
  };
  auto compute = [&](const int kb, const bf16x8 qf[2][2], const f32x4 lv[2]) {
#pragma unroll
    for (int ih = 0; ih < 4; ih += 2) {  // halves: keeps sacc liveness small
      f32x4 sacc[2][2];
#pragma unroll
      for (int ii = 0; ii < 2; ++ii)
#pragma unroll
        for (int qi = 0; qi < 2; ++qi)
          sacc[ii][qi] = (f32x4){0.f, 0.f, 0.f, 0.f};
      __builtin_amdgcn_s_setprio(1);
#pragma unroll
      for (int kp = 0; kp < 2; ++kp)
#pragma unroll
        for (int ii = 0; ii < 2; ++ii) {
          const bf16x8 kf = lds8(&SM[kb + fof[kp][ih + ii]]);
#pragma unroll
          for (int qi = 0; qi < 2; ++qi)
            sacc[ii][qi] = __builtin_amdgcn_mfma_f32_16x16x32_bf16(
                kf, qf[kp][qi], sacc[ii][qi], 0, 0, 0);
        }
      __builtin_amdgcn_s_setprio(0);
#pragma unroll
      for (int ii = 0; ii < 2; ++ii)
#pragma unroll
        for (int qi = 0; qi < 2; ++qi)
#pragma unroll
          for (int r = 0; r < 4; ++r)
            sc[ih + ii][qi][r] += exp2f(sacc[ii][qi][r]) * lv[qi][r];
    }
  };

  bf16x8 qA[2][2], qB[2][2];
  f32x4 lvA[2], lvB[2];
  stage(0, 0);
  ldq(qA, lvA, 0);
  __syncthreads();
#pragma unroll 1
  for (int h = 0; h < Hh; h += 2) {
    stage(1, h + 1);
    ldq(qB, lvB, h + 1);
    compute(0, qA, lvA);
    __syncthreads();
    if (h + 2 < Hh) {
      stage(0, h + 2);
      ldq(qA, lvA, h + 2);
    }
    compute(4096, qB, lvB);
    __syncthreads();
  }

  constexpr float invH = 1.0f / 12.0f;
#pragma unroll
  for (int i = 0; i < 4; ++i)
#pragma unroll
    for (int qi = 0; qi < 2; ++qi) {
      f32x4 o;
#pragma unroll
      for (int r = 0; r < 4; ++r) o[r] = sc[i][qi][r] * invH;
      *(f32x4*)&score[((size_t)b * Nn + qw + qi * 16 + lr) * Nn + kv0 +
                      i * 16 + 4 * lh] = o;
    }
}

// ---------------------------------------------------------------------------
// Proj GEMM: out[m][c] = sum_k OH[m][k]*pw[c][k] + bias[c]
// ---------------------------------------------------------------------------
__global__ __launch_bounds__(256) void proj_mfma(
    const short* __restrict__ A, const short* __restrict__ W,
    const float* __restrict__ bias, float* __restrict__ out) {
  __shared__ short As[128 * 64];
  __shared__ short Bs[128 * 64];
  const int t = threadIdx.x, l = t & 63, w = t >> 6;
  const int lr = l & 15, lh = l >> 4;
  const int m0 = blockIdx.x * 128, c0 = blockIdx.y * 128;
  const int wr = w >> 1, wc = w & 1;
  f32x4 acc[4][4];
#pragma unroll
  for (int i = 0; i < 4; ++i)
#pragma unroll
    for (int j = 0; j < 4; ++j) acc[i][j] = (f32x4){0.f, 0.f, 0.f, 0.f};

  for (int k0 = 0; k0 < Cc; k0 += 64) {
    __syncthreads();
#pragma unroll
    for (int u = 0; u < 4; ++u) {
      const int du = (w * 4 + u) * 64 + l;
      const int row = du >> 3, ch = du & 7, sch = ch ^ (row & 7);
      gl_lds16(A + (size_t)(m0 + row) * Cc + k0 + sch * 8,
               &As[(w * 4 + u) * 512]);
      gl_lds16(W + (size_t)(c0 + row) * Cc + k0 + sch * 8,
               &Bs[(w * 4 + u) * 512]);
    }
    __syncthreads();
#pragma unroll
    for (int kp = 0; kp < 2; ++kp) {
      bf16x8 af[4], bfv[4];
#pragma unroll
      for (int i = 0; i < 4; ++i)
        af[i] = ld_frag(As, wr * 64 + i * 16 + lr, kp * 4 + lh);
#pragma unroll
      for (int j = 0; j < 4; ++j)
        bfv[j] = ld_frag(Bs, wc * 64 + j * 16 + lr, kp * 4 + lh);
#pragma unroll
      for (int i = 0; i < 4; ++i)
#pragma unroll
        for (int j = 0; j < 4; ++j)
          acc[i][j] = __builtin_amdgcn_mfma_f32_16x16x32_bf16(
              af[i], bfv[j], acc[i][j], 0, 0, 0);
    }
  }
#pragma unroll
  for (int j = 0; j < 4; ++j) {
    const int c = c0 + wc * 64 + j * 16 + lr;
    const float bi = bias[c];
#pragma unroll
    for (int i = 0; i < 4; ++i)
#pragma unroll
      for (int r = 0; r < 4; ++r) {
        const int m = m0 + wr * 64 + i * 16 + lh * 4 + r;
        out[(size_t)m * Cc + c] = acc[i][j][r] + bi;
      }
  }
}

// ---------------------------------------------------------------------------
extern "C" void kernel_launch(void* const* d_in, const int* in_sizes, int n_in,
                              void* d_out, int out_size, void* d_ws,
                              size_t ws_size, hipStream_t stream) {
  const float* x = (const float*)d_in[0];
  const float* qkv_w = (const float*)d_in[1];
  const float* proj_w = (const float*)d_in[2];
  const float* proj_b = (const float*)d_in[3];

  float* out = (float*)d_out;
  float* score = out + (size_t)Bb * Nn * Cc;

  const size_t nx = (size_t)Bb * Nn * Cc;
  const size_t nwq = (size_t)3 * Cc * Cc;
  const size_t npw = (size_t)Cc * Cc;
  short* xb = (short*)d_ws;
  short* wqb = xb + nx;
  short* pwb = wqb + nwq;
  short* Qb = pwb + npw;
  short* Kb = Qb + nx;
  short* Vtb = Kb + nx;
  short* OHb = Vtb + nx;
  float* Linv = (float*)(OHb + nx);

  cvt_kernel<<<dim3((int)(nx / 1024)), 256, 0, stream>>>(x, xb);
  cvt_kernel<<<dim3((int)(nwq / 1024)), 256, 0, stream>>>(qkv_w, wqb);
  cvt_kernel<<<dim3((int)(npw / 1024)), 256, 0, stream>>>(proj_w, pwb);
  qkv_mfma<<<dim3(32, 18), 256, 0, stream>>>(xb, wqb, Qb, Kb, Vtb);
  attn_pass1<<<dim3(Bb * Hh * 32), 128, 0, stream>>>(Qb, Kb, Vtb, Linv, OHb);
  score_mfma<<<dim3(1024), 256, 0, stream>>>(Qb, Kb, Linv, score);
  proj_mfma<<<dim3(32, 6), 256, 0, stream>>>(OHb, pwb, proj_b, out);
}

// Round 5
// 155.150 us; speedup vs baseline: 1.2633x; 1.2633x over previous
//
#include <hip/hip_runtime.h>
#include <cstddef>

// B,N,C,H = 2,2048,768,12; HD=64.  bf16 MFMA everywhere, fp32 accum.
typedef __attribute__((ext_vector_type(8))) short bf16x8;
typedef __attribute__((ext_vector_type(4))) float f32x4;

constexpr int Bb = 2, Nn = 2048, Cc = 768, Hh = 12, HDd = 64;
// 0.125 (HD^-1/2) * log2(e): softmax via exp2, mul folded into Q.
constexpr float QSCALE = 0.125f * 1.44269504088896340736f;

__device__ inline short f2bf(float f) {
  unsigned u = __builtin_bit_cast(unsigned, f);
  u += 0x7fff + ((u >> 16) & 1);  // RNE
  return (short)(u >> 16);
}
__device__ inline unsigned cvtpk(float a, float b) {
  unsigned r;
  asm("v_cvt_pk_bf16_f32 %0, %1, %2" : "=v"(r) : "v"(a), "v"(b));
  return r;
}
__device__ inline void gl_lds16(const void* g, void* l) {
  __builtin_amdgcn_global_load_lds(
      (const __attribute__((address_space(1))) unsigned*)g,
      (__attribute__((address_space(3))) unsigned*)l, 16, 0, 0);
}
__device__ inline bf16x8 lds8(const short* p) { return *(const bf16x8*)p; }
__device__ inline bf16x8 ld_frag(const short* base, int row, int ch) {
  return *(const bf16x8*)&base[row * 64 + (((ch ^ (row & 7)) << 3))];
}

// ---------------------------------------------------------------------------
// f32 -> bf16 convert
// ---------------------------------------------------------------------------
__global__ __launch_bounds__(256) void cvt_kernel(const float* __restrict__ s,
                                                  short* __restrict__ d) {
  const int i = (blockIdx.x * 256 + threadIdx.x) * 4;
  const float4 v = *(const float4*)&s[i];
  short4 o;
  o.x = f2bf(v.x); o.y = f2bf(v.y); o.z = f2bf(v.z); o.w = f2bf(v.w);
  *(short4*)&d[i] = o;
}

// ---------------------------------------------------------------------------
// QKV GEMM: scatter into Q (pre-scaled by QSCALE), K (B,H,N,64) and
// V transposed (B,H,64,N).  128x128 tile, BK=64, 4 waves.  (proven r2-r4)
// ---------------------------------------------------------------------------
__global__ __launch_bounds__(256) void qkv_mfma(
    const short* __restrict__ A, const short* __restrict__ W,
    short* __restrict__ Qg, short* __restrict__ Kg, short* __restrict__ Vtg) {
  __shared__ short As[128 * 64];
  __shared__ short Bs[128 * 64];
  const int t = threadIdx.x, l = t & 63, w = t >> 6;
  const int lr = l & 15, lh = l >> 4;
  const int m0 = blockIdx.x * 128, r0 = blockIdx.y * 128;
  const int wr = w >> 1, wc = w & 1;
  f32x4 acc[4][4];
#pragma unroll
  for (int i = 0; i < 4; ++i)
#pragma unroll
    for (int j = 0; j < 4; ++j) acc[i][j] = (f32x4){0.f, 0.f, 0.f, 0.f};

  for (int k0 = 0; k0 < Cc; k0 += 64) {
    __syncthreads();
#pragma unroll
    for (int u = 0; u < 4; ++u) {
      const int du = (w * 4 + u) * 64 + l;
      const int row = du >> 3, ch = du & 7, sch = ch ^ (row & 7);
      gl_lds16(A + (size_t)(m0 + row) * Cc + k0 + sch * 8,
               &As[(w * 4 + u) * 512]);
      gl_lds16(W + (size_t)(r0 + row) * Cc + k0 + sch * 8,
               &Bs[(w * 4 + u) * 512]);
    }
    __syncthreads();
#pragma unroll
    for (int kp = 0; kp < 2; ++kp) {
      bf16x8 af[4], bfv[4];
#pragma unroll
      for (int i = 0; i < 4; ++i)
        af[i] = ld_frag(As, wr * 64 + i * 16 + lr, kp * 4 + lh);
#pragma unroll
      for (int j = 0; j < 4; ++j)
        bfv[j] = ld_frag(Bs, wc * 64 + j * 16 + lr, kp * 4 + lh);
#pragma unroll
      for (int i = 0; i < 4; ++i)
#pragma unroll
        for (int j = 0; j < 4; ++j)
          acc[i][j] = __builtin_amdgcn_mfma_f32_16x16x32_bf16(
              af[i], bfv[j], acc[i][j], 0, 0, 0);
    }
  }
  const int which = r0 / Cc;  // 128 | 768: block-uniform
  const int rbase = r0 % Cc;
  const int bq = m0 >> 11;
  const int nb = (m0 & 2047) + wr * 64;
  if (which == 2) {  // V: transposed layout -> short4 stores along n
#pragma unroll
    for (int j = 0; j < 4; ++j) {
      const int rr = rbase + wc * 64 + j * 16 + lr;
      const int head = rr >> 6, dd = rr & 63;
      short* vp = &Vtg[(((size_t)bq * Hh + head) * HDd + dd) * Nn];
#pragma unroll
      for (int i = 0; i < 4; ++i) {
        short4 o;
        o.x = f2bf(acc[i][j][0]); o.y = f2bf(acc[i][j][1]);
        o.z = f2bf(acc[i][j][2]); o.w = f2bf(acc[i][j][3]);
        *(short4*)&vp[nb + i * 16 + lh * 4] = o;
      }
    }
  } else {
    const float scl = (which == 0) ? QSCALE : 1.0f;
    short* __restrict__ dst = (which == 0) ? Qg : Kg;
#pragma unroll
    for (int j = 0; j < 4; ++j) {
      const int rr = rbase + wc * 64 + j * 16 + lr;
      const int head = rr >> 6, dd = rr & 63;
      short* dp = &dst[((size_t)bq * Hh + head) * Nn * HDd + dd];
#pragma unroll
      for (int i = 0; i < 4; ++i)
#pragma unroll
        for (int r = 0; r < 4; ++r)
          dp[(size_t)(nb + i * 16 + lh * 4 + r) * HDd] =
              f2bf(acc[i][j][r] * scl);
    }
  }
}

// ---------------------------------------------------------------------------
// Attention pass 1.  256 threads = 4 waves; block q-tile 128, 32 q per wave.
// Q in regs (2kp x 2qi); K/V double-buffered LDS; per-wave P in LDS;
// kf/vf frags shared across both q-fragments (halves LDS bytes per output);
// L via mfma(P, ones) -> fully lane-local normalization.
// ---------------------------------------------------------------------------
__global__ __launch_bounds__(256, 2) void attn_pass1(
    const short* __restrict__ Qg, const short* __restrict__ Kg,
    const short* __restrict__ Vtg, float* __restrict__ Linv,
    short* __restrict__ OHb) {
  // shorts: [buf0: K4096|V4096][buf1: K4096|V4096][P: 4 waves x 2048]
  __shared__ short SM[2 * 8192 + 4 * 2048];
  const int t = threadIdx.x, l = t & 63, w = t >> 6;
  const int lr = l & 15, lh = l >> 4;
  // XCD swizzle: 384 blocks, 48 per XCD (16 consecutive share one head's K/V)
  const int raw = blockIdx.x;
  const int bid = (raw & 7) * 48 + (raw >> 3);
  const int q0 = (bid & 15) * 128;
  const int head = (bid >> 4) % Hh;
  const int b = bid / (16 * Hh);
  const size_t base = (size_t)b * Hh + head;
  const short* Qh = Qg + base * Nn * HDd;
  const short* Kh = Kg + base * Nn * HDd;
  const short* Vh = Vtg + base * HDd * Nn;
  const int qw = q0 + w * 32;
  const int PB = 16384 + w * 2048;

  const bf16x8 onesf = {0x3F80, 0x3F80, 0x3F80, 0x3F80,
                        0x3F80, 0x3F80, 0x3F80, 0x3F80};

  int fof[2][4], wofi[4];
#pragma unroll
  for (int kp = 0; kp < 2; ++kp)
#pragma unroll
    for (int i = 0; i < 4; ++i)
      fof[kp][i] = (i * 16 + lr) * 64 + (((kp * 4 + lh) ^ (lr & 7)) << 3);
#pragma unroll
  for (int i = 0; i < 4; ++i) {
    const int ch = 2 * i + (lh >> 1);
    wofi[i] = lr * 64 + ((ch ^ (lr & 7)) << 3) + (lh & 1) * 4;
  }
  const int pof0 = lr * 64 + ((lh ^ (lr & 7)) << 3);
  const int pof1 = lr * 64 + (((4 + lh) ^ (lr & 7)) << 3);

  bf16x8 qf[2][2];
#pragma unroll
  for (int kp = 0; kp < 2; ++kp)
#pragma unroll
    for (int qi = 0; qi < 2; ++qi)
      qf[kp][qi] = *(const bf16x8*)&Qh[(size_t)(qw + qi * 16 + lr) * HDd +
                                       kp * 32 + lh * 8];

  f32x4 accO[2][4], accL[2];
#pragma unroll
  for (int qi = 0; qi < 2; ++qi) {
    accL[qi] = (f32x4){0.f, 0.f, 0.f, 0.f};
#pragma unroll
    for (int j = 0; j < 4; ++j) accO[qi][j] = (f32x4){0.f, 0.f, 0.f, 0.f};
  }

  auto stage = [&](const int buf, const int tile) {
    const short* Kt = Kh + (size_t)tile * (64 * HDd);
    const short* Vt = Vh + tile * 64;
#pragma unroll
    for (int u = 0; u < 2; ++u) {
      const int cu = u * 4 + w;
      const int du = cu * 64 + l;
      const int row = du >> 3, ch = du & 7, sch = ch ^ (row & 7);
      gl_lds16(Kt + row * 64 + sch * 8, &SM[buf * 8192 + cu * 512]);
      gl_lds16(Vt + (size_t)row * Nn + sch * 8,
               &SM[buf * 8192 + 4096 + cu * 512]);
    }
  };

  auto compute = [&](const int kb) {  // kb: 0 or 8192
    f32x4 sacc[4][2];
#pragma unroll
    for (int i = 0; i < 4; ++i)
#pragma unroll
      for (int qi = 0; qi < 2; ++qi) sacc[i][qi] = (f32x4){0.f, 0.f, 0.f, 0.f};
    __builtin_amdgcn_s_setprio(1);
#pragma unroll
    for (int kp = 0; kp < 2; ++kp)
#pragma unroll
      for (int i = 0; i < 4; ++i) {
        const bf16x8 kf = lds8(&SM[kb + fof[kp][i]]);
        sacc[i][0] = __builtin_amdgcn_mfma_f32_16x16x32_bf16(
            kf, qf[kp][0], sacc[i][0], 0, 0, 0);
        sacc[i][1] = __builtin_amdgcn_mfma_f32_16x16x32_bf16(
            kf, qf[kp][1], sacc[i][1], 0, 0, 0);
      }
    __builtin_amdgcn_s_setprio(0);
#pragma unroll
    for (int i = 0; i < 4; ++i)
#pragma unroll
      for (int qi = 0; qi < 2; ++qi) {
        const float p0 = exp2f(sacc[i][qi][0]), p1 = exp2f(sacc[i][qi][1]);
        const float p2 = exp2f(sacc[i][qi][2]), p3 = exp2f(sacc[i][qi][3]);
        uint2 pk;
        pk.x = cvtpk(p0, p1);
        pk.y = cvtpk(p2, p3);
        *(uint2*)&SM[PB + qi * 1024 + wofi[i]] = pk;
      }
    __builtin_amdgcn_s_setprio(1);
#pragma unroll
    for (int kp = 0; kp < 2; ++kp) {
      const bf16x8 pa0 = lds8(&SM[PB + (kp ? pof1 : pof0)]);
      const bf16x8 pa1 = lds8(&SM[PB + 1024 + (kp ? pof1 : pof0)]);
      accL[0] = __builtin_amdgcn_mfma_f32_16x16x32_bf16(pa0, onesf, accL[0],
                                                        0, 0, 0);
      accL[1] = __builtin_amdgcn_mfma_f32_16x16x32_bf16(pa1, onesf, accL[1],
                                                        0, 0, 0);
#pragma unroll
      for (int j = 0; j < 4; ++j) {
        const bf16x8 vf = lds8(&SM[kb + 4096 + fof[kp][j]]);
        accO[0][j] = __builtin_amdgcn_mfma_f32_16x16x32_bf16(pa0, vf,
                                                             accO[0][j], 0, 0, 0);
        accO[1][j] = __builtin_amdgcn_mfma_f32_16x16x32_bf16(pa1, vf,
                                                             accO[1][j], 0, 0, 0);
      }
    }
    __builtin_amdgcn_s_setprio(0);
  };

  stage(0, 0);
  __syncthreads();
#pragma unroll 1
  for (int it = 0; it < Nn / 64; it += 2) {
    stage(1, it + 1);
    compute(0);
    __syncthreads();
    if (it + 2 < Nn / 64) stage(0, it + 2);
    compute(8192);
    __syncthreads();
  }

#pragma unroll
  for (int qi = 0; qi < 2; ++qi) {
    f32x4 linvq;
#pragma unroll
    for (int r = 0; r < 4; ++r) linvq[r] = 1.0f / accL[qi][r];
    if (lr == 0)
      *(f32x4*)&Linv[base * Nn + qw + qi * 16 + 4 * lh] = linvq;
#pragma unroll
    for (int j = 0; j < 4; ++j)
#pragma unroll
      for (int r = 0; r < 4; ++r)
        OHb[((size_t)b * Nn + qw + qi * 16 + 4 * lh + r) * Cc + head * HDd +
            j * 16 + lr] = f2bf(accO[qi][j][r] * linvq[r]);
  }
}

// ---------------------------------------------------------------------------
// Score: score[b][q][kv] = (1/H) sum_h 2^(qk) * Linv[b,h,q].
// Block: 128 q x 64 kv; 4 waves x 32 q.  K dbuf in LDS; Q + Linv direct from
// global into named scalar regs (by-value lambda args -> no spill).
// Correct Linv: q = lane&15 in the mfma(K,Q) D-layout -> per-lane scalar.
// Output staged in LDS, written as contiguous 256B row chunks.
// ---------------------------------------------------------------------------
__global__ __launch_bounds__(256, 3) void score_mfma(
    const short* __restrict__ Qg, const short* __restrict__ Kg,
    const float* __restrict__ Linv, float* __restrict__ score) {
  __shared__ __align__(16) char SMraw[128 * 72 * 4];  // 36864 B
  short* SK = (short*)SMraw;   // K dbuf: 2 x 4096 shorts (16 KB)
  float* SMf = (float*)SMraw;  // out staging [128][72], used after the loop
  const int t = threadIdx.x, l = t & 63, w = t >> 6;
  const int lr = l & 15, lh = l >> 4;
  // XCD map: xcd owns (b = xcd>>2, 4 q-tiles) x all kv -> K panel 3.1MB in L2
  const int raw = blockIdx.x;  // 1024
  const int xcd = raw & 7, idx = raw >> 3;
  const int b = xcd >> 2;
  const int q0 = ((xcd & 3) * 4 + (idx >> 5)) * 128;
  const int kv0 = (idx & 31) * 64;
  const int qw = q0 + w * 32;

  int fof[2][4];
#pragma unroll
  for (int kp = 0; kp < 2; ++kp)
#pragma unroll
    for (int i = 0; i < 4; ++i)
      fof[kp][i] = (i * 16 + lr) * 64 + (((kp * 4 + lh) ^ (lr & 7)) << 3);

  f32x4 sc[4][2];
#pragma unroll
  for (int i = 0; i < 4; ++i)
#pragma unroll
    for (int qi = 0; qi < 2; ++qi) sc[i][qi] = (f32x4){0.f, 0.f, 0.f, 0.f};

  auto stage = [&](const int buf, const int h) {
    const short* Kt = Kg + (((size_t)b * Hh + h) * Nn + kv0) * HDd;
#pragma unroll
    for (int u = 0; u < 2; ++u) {
      const int cu = u * 4 + w;
      const int du = cu * 64 + l;
      const int row = du >> 3, ch = du & 7, sch = ch ^ (row & 7);
      gl_lds16(Kt + row * 64 + sch * 8, &SK[buf * 4096 + cu * 512]);
    }
  };
  auto ldq = [&](const int h, bf16x8& q00, bf16x8& q01, bf16x8& q10,
                 bf16x8& q11, float& l0, float& l1) {
    const size_t hb = (size_t)b * Hh + h;
    q00 = *(const bf16x8*)&Qg[(hb * Nn + qw + lr) * HDd + lh * 8];
    q01 = *(const bf16x8*)&Qg[(hb * Nn + qw + 16 + lr) * HDd + lh * 8];
    q10 = *(const bf16x8*)&Qg[(hb * Nn + qw + lr) * HDd + 32 + lh * 8];
    q11 = *(const bf16x8*)&Qg[(hb * Nn + qw + 16 + lr) * HDd + 32 + lh * 8];
    l0 = Linv[hb * Nn + qw + lr];
    l1 = Linv[hb * Nn + qw + 16 + lr];
  };
  auto compute = [&](const int kb, const bf16x8 q00, const bf16x8 q01,
                     const bf16x8 q10, const bf16x8 q11, const float l0,
                     const float l1) {
    f32x4 sacc[4][2];
#pragma unroll
    for (int i = 0; i < 4; ++i)
#pragma unroll
      for (int qi = 0; qi < 2; ++qi) sacc[i][qi] = (f32x4){0.f, 0.f, 0.f, 0.f};
    __builtin_amdgcn_s_setprio(1);
#pragma unroll
    for (int i = 0; i < 4; ++i) {
      const bf16x8 kf0 = lds8(&SK[kb + fof[0][i]]);
      sacc[i][0] = __builtin_amdgcn_mfma_f32_16x16x32_bf16(kf0, q00,
                                                           sacc[i][0], 0, 0, 0);
      sacc[i][1] = __builtin_amdgcn_mfma_f32_16x16x32_bf16(kf0, q01,
                                                           sacc[i][1], 0, 0, 0);
    }
#pragma unroll
    for (int i = 0; i < 4; ++i) {
      const bf16x8 kf1 = lds8(&SK[kb + fof[1][i]]);
      sacc[i][0] = __builtin_amdgcn_mfma_f32_16x16x32_bf16(kf1, q10,
                                                           sacc[i][0], 0, 0, 0);
      sacc[i][1] = __builtin_amdgcn_mfma_f32_16x16x32_bf16(kf1, q11,
                                                           sacc[i][1], 0, 0, 0);
    }
    __builtin_amdgcn_s_setprio(0);
#pragma unroll
    for (int i = 0; i < 4; ++i)
#pragma unroll
      for (int r = 0; r < 4; ++r) {
        sc[i][0][r] += exp2f(sacc[i][0][r]) * l0;
        sc[i][1][r] += exp2f(sacc[i][1][r]) * l1;
      }
  };

  bf16x8 qA00, qA01, qA10, qA11, qB00, qB01, qB10, qB11;
  float lA0, lA1, lB0, lB1;
  stage(0, 0);
  ldq(0, qA00, qA01, qA10, qA11, lA0, lA1);
  __syncthreads();
#pragma unroll 1
  for (int h = 0; h < Hh; h += 2) {
    stage(1, h + 1);
    ldq(h + 1, qB00, qB01, qB10, qB11, lB0, lB1);
    compute(0, qA00, qA01, qA10, qA11, lA0, lA1);
    __syncthreads();
    if (h + 2 < Hh) {
      stage(0, h + 2);
      ldq(h + 2, qA00, qA01, qA10, qA11, lA0, lA1);
    }
    compute(4096, qB00, qB01, qB10, qB11, lB0, lB1);
    __syncthreads();
  }

  // stage sc -> LDS [q_local 128][72], then coalesced contiguous stores
  constexpr float invH = 1.0f / 12.0f;
#pragma unroll
  for (int i = 0; i < 4; ++i)
#pragma unroll
    for (int qi = 0; qi < 2; ++qi) {
      f32x4 o;
#pragma unroll
      for (int r = 0; r < 4; ++r) o[r] = sc[i][qi][r] * invH;
      *(f32x4*)&SMf[(w * 32 + qi * 16 + lr) * 72 + i * 16 + 4 * lh] = o;
    }
  __syncthreads();
#pragma unroll
  for (int s = 0; s < 8; ++s) {
    const int lin = t + s * 256;
    const int row = lin >> 4, ch = lin & 15;  // 16 threads cover one row's 256B
    const f32x4 v = *(const f32x4*)&SMf[row * 72 + ch * 4];
    *(f32x4*)&score[((size_t)b * Nn + q0 + row) * Nn + kv0 + ch * 4] = v;
  }
}

// ---------------------------------------------------------------------------
// Proj GEMM: out[m][c] = sum_k OH[m][k]*pw[c][k] + bias[c]
// ---------------------------------------------------------------------------
__global__ __launch_bounds__(256) void proj_mfma(
    const short* __restrict__ A, const short* __restrict__ W,
    const float* __restrict__ bias, float* __restrict__ out) {
  __shared__ short As[128 * 64];
  __shared__ short Bs[128 * 64];
  const int t = threadIdx.x, l = t & 63, w = t >> 6;
  const int lr = l & 15, lh = l >> 4;
  const int m0 = blockIdx.x * 128, c0 = blockIdx.y * 128;
  const int wr = w >> 1, wc = w & 1;
  f32x4 acc[4][4];
#pragma unroll
  for (int i = 0; i < 4; ++i)
#pragma unroll
    for (int j = 0; j < 4; ++j) acc[i][j] = (f32x4){0.f, 0.f, 0.f, 0.f};

  for (int k0 = 0; k0 < Cc; k0 += 64) {
    __syncthreads();
#pragma unroll
    for (int u = 0; u < 4; ++u) {
      const int du = (w * 4 + u) * 64 + l;
      const int row = du >> 3, ch = du & 7, sch = ch ^ (row & 7);
      gl_lds16(A + (size_t)(m0 + row) * Cc + k0 + sch * 8,
               &As[(w * 4 + u) * 512]);
      gl_lds16(W + (size_t)(c0 + row) * Cc + k0 + sch * 8,
               &Bs[(w * 4 + u) * 512]);
    }
    __syncthreads();
#pragma unroll
    for (int kp = 0; kp < 2; ++kp) {
      bf16x8 af[4], bfv[4];
#pragma unroll
      for (int i = 0; i < 4; ++i)
        af[i] = ld_frag(As, wr * 64 + i * 16 + lr, kp * 4 + lh);
#pragma unroll
      for (int j = 0; j < 4; ++j)
        bfv[j] = ld_frag(Bs, wc * 64 + j * 16 + lr, kp * 4 + lh);
#pragma unroll
      for (int i = 0; i < 4; ++i)
#pragma unroll
        for (int j = 0; j < 4; ++j)
          acc[i][j] = __builtin_amdgcn_mfma_f32_16x16x32_bf16(
              af[i], bfv[j], acc[i][j], 0, 0, 0);
    }
  }
#pragma unroll
  for (int j = 0; j < 4; ++j) {
    const int c = c0 + wc * 64 + j * 16 + lr;
    const float bi = bias[c];
#pragma unroll
    for (int i = 0; i < 4; ++i)
#pragma unroll
      for (int r = 0; r < 4; ++r) {
        const int m = m0 + wr * 64 + i * 16 + lh * 4 + r;
        out[(size_t)m * Cc + c] = acc[i][j][r] + bi;
      }
  }
}

// ---------------------------------------------------------------------------
extern "C" void kernel_launch(void* const* d_in, const int* in_sizes, int n_in,
                              void* d_out, int out_size, void* d_ws,
                              size_t ws_size, hipStream_t stream) {
  const float* x = (const float*)d_in[0];
  const float* qkv_w = (const float*)d_in[1];
  const float* proj_w = (const float*)d_in[2];
  const float* proj_b = (const float*)d_in[3];

  float* out = (float*)d_out;
  float* score = out + (size_t)Bb * Nn * Cc;

  const size_t nx = (size_t)Bb * Nn * Cc;
  const size_t nwq = (size_t)3 * Cc * Cc;
  const size_t npw = (size_t)Cc * Cc;
  short* xb = (short*)d_ws;
  short* wqb = xb + nx;
  short* pwb = wqb + nwq;
  short* Qb = pwb + npw;
  short* Kb = Qb + nx;
  short* Vtb = Kb + nx;
  short* OHb = Vtb + nx;
  float* Linv = (float*)(OHb + nx);

  cvt_kernel<<<dim3((int)(nx / 1024)), 256, 0, stream>>>(x, xb);
  cvt_kernel<<<dim3((int)(nwq / 1024)), 256, 0, stream>>>(qkv_w, wqb);
  cvt_kernel<<<dim3((int)(npw / 1024)), 256, 0, stream>>>(proj_w, pwb);
  qkv_mfma<<<dim3(32, 18), 256, 0, stream>>>(xb, wqb, Qb, Kb, Vtb);
  attn_pass1<<<dim3(384), 256, 0, stream>>>(Qb, Kb, Vtb, Linv, OHb);
  score_mfma<<<dim3(1024), 256, 0, stream>>>(Qb, Kb, Linv, score);
  proj_mfma<<<dim3(32, 6), 256, 0, stream>>>(OHb, pwb, proj_b, out);
}

// Round 6
// 143.948 us; speedup vs baseline: 1.3616x; 1.0778x over previous
//
#include <hip/hip_runtime.h>
#include <cstddef>

// B,N,C,H = 2,2048,768,12; HD=64.  bf16 MFMA everywhere, fp32 accum.
typedef __attribute__((ext_vector_type(8))) short bf16x8;
typedef __attribute__((ext_vector_type(4))) float f32x4;

constexpr int Bb = 2, Nn = 2048, Cc = 768, Hh = 12, HDd = 64;
// 0.125 (HD^-1/2) * log2(e): softmax via exp2, mul folded into Q.
constexpr float QSCALE = 0.125f * 1.44269504088896340736f;

__device__ inline short f2bf(float f) {
  unsigned u = __builtin_bit_cast(unsigned, f);
  u += 0x7fff + ((u >> 16) & 1);  // RNE
  return (short)(u >> 16);
}
__device__ inline unsigned cvtpk(float a, float b) {
  unsigned r;
  asm("v_cvt_pk_bf16_f32 %0, %1, %2" : "=v"(r) : "v"(a), "v"(b));
  return r;
}
__device__ inline void gl_lds16(const void* g, void* l) {
  __builtin_amdgcn_global_load_lds(
      (const __attribute__((address_space(1))) unsigned*)g,
      (__attribute__((address_space(3))) unsigned*)l, 16, 0, 0);
}
__device__ inline bf16x8 lds8(const short* p) { return *(const bf16x8*)p; }
__device__ inline bf16x8 ld_frag(const short* base, int row, int ch) {
  return *(const bf16x8*)&base[row * 64 + (((ch ^ (row & 7)) << 3))];
}

// ---------------------------------------------------------------------------
// f32 -> bf16 convert
// ---------------------------------------------------------------------------
__global__ __launch_bounds__(256) void cvt_kernel(const float* __restrict__ s,
                                                  short* __restrict__ d) {
  const int i = (blockIdx.x * 256 + threadIdx.x) * 4;
  const float4 v = *(const float4*)&s[i];
  short4 o;
  o.x = f2bf(v.x); o.y = f2bf(v.y); o.z = f2bf(v.z); o.w = f2bf(v.w);
  *(short4*)&d[i] = o;
}

// ---------------------------------------------------------------------------
// QKV GEMM: scatter into Q (pre-scaled by QSCALE), K (B,H,N,64) and
// V transposed (B,H,64,N).  128x128 tile, BK=64, 4 waves.  (proven r2-r5)
// ---------------------------------------------------------------------------
__global__ __launch_bounds__(256) void qkv_mfma(
    const short* __restrict__ A, const short* __restrict__ W,
    short* __restrict__ Qg, short* __restrict__ Kg, short* __restrict__ Vtg) {
  __shared__ short As[128 * 64];
  __shared__ short Bs[128 * 64];
  const int t = threadIdx.x, l = t & 63, w = t >> 6;
  const int lr = l & 15, lh = l >> 4;
  const int m0 = blockIdx.x * 128, r0 = blockIdx.y * 128;
  const int wr = w >> 1, wc = w & 1;
  f32x4 acc[4][4];
#pragma unroll
  for (int i = 0; i < 4; ++i)
#pragma unroll
    for (int j = 0; j < 4; ++j) acc[i][j] = (f32x4){0.f, 0.f, 0.f, 0.f};

  for (int k0 = 0; k0 < Cc; k0 += 64) {
    __syncthreads();
#pragma unroll
    for (int u = 0; u < 4; ++u) {
      const int du = (w * 4 + u) * 64 + l;
      const int row = du >> 3, ch = du & 7, sch = ch ^ (row & 7);
      gl_lds16(A + (size_t)(m0 + row) * Cc + k0 + sch * 8,
               &As[(w * 4 + u) * 512]);
      gl_lds16(W + (size_t)(r0 + row) * Cc + k0 + sch * 8,
               &Bs[(w * 4 + u) * 512]);
    }
    __syncthreads();
#pragma unroll
    for (int kp = 0; kp < 2; ++kp) {
      bf16x8 af[4], bfv[4];
#pragma unroll
      for (int i = 0; i < 4; ++i)
        af[i] = ld_frag(As, wr * 64 + i * 16 + lr, kp * 4 + lh);
#pragma unroll
      for (int j = 0; j < 4; ++j)
        bfv[j] = ld_frag(Bs, wc * 64 + j * 16 + lr, kp * 4 + lh);
#pragma unroll
      for (int i = 0; i < 4; ++i)
#pragma unroll
        for (int j = 0; j < 4; ++j)
          acc[i][j] = __builtin_amdgcn_mfma_f32_16x16x32_bf16(
              af[i], bfv[j], acc[i][j], 0, 0, 0);
    }
  }
  const int which = r0 / Cc;  // 128 | 768: block-uniform
  const int rbase = r0 % Cc;
  const int bq = m0 >> 11;
  const int nb = (m0 & 2047) + wr * 64;
  if (which == 2) {  // V: transposed layout -> short4 stores along n
#pragma unroll
    for (int j = 0; j < 4; ++j) {
      const int rr = rbase + wc * 64 + j * 16 + lr;
      const int head = rr >> 6, dd = rr & 63;
      short* vp = &Vtg[(((size_t)bq * Hh + head) * HDd + dd) * Nn];
#pragma unroll
      for (int i = 0; i < 4; ++i) {
        short4 o;
        o.x = f2bf(acc[i][j][0]); o.y = f2bf(acc[i][j][1]);
        o.z = f2bf(acc[i][j][2]); o.w = f2bf(acc[i][j][3]);
        *(short4*)&vp[nb + i * 16 + lh * 4] = o;
      }
    }
  } else {
    const float scl = (which == 0) ? QSCALE : 1.0f;
    short* __restrict__ dst = (which == 0) ? Qg : Kg;
#pragma unroll
    for (int j = 0; j < 4; ++j) {
      const int rr = rbase + wc * 64 + j * 16 + lr;
      const int head = rr >> 6, dd = rr & 63;
      short* dp = &dst[((size_t)bq * Hh + head) * Nn * HDd + dd];
#pragma unroll
      for (int i = 0; i < 4; ++i)
#pragma unroll
        for (int r = 0; r < 4; ++r)
          dp[(size_t)(nb + i * 16 + lh * 4 + r) * HDd] =
              f2bf(acc[i][j][r] * scl);
    }
  }
}

// ---------------------------------------------------------------------------
// Attention pass 1.  Grid 768 = (b, head, 64-q tile); 4 waves x 16 q.
// Phase-shifted pipeline: body(t) = stage(K t+1, V t) ; QK(t) ; exp(t-1) ;
// PV(t-1).  QK MFMAs are independent of exp/PV -> pipes overlap within a
// wave.  K dbuf, V dbuf delayed one tile, per-wave P in LDS, L via
// mfma(P, ones) -> lane-local normalization.  No setprio (it fences sched).
// ---------------------------------------------------------------------------
__global__ __launch_bounds__(256, 3) void attn_pass1(
    const short* __restrict__ Qg, const short* __restrict__ Kg,
    const short* __restrict__ Vtg, float* __restrict__ Linv,
    short* __restrict__ OHb) {
  // shorts: [K0 4096][K1 4096][V0 4096][V1 4096][P: 4 waves x 1024]
  __shared__ short SM[4 * 4096 + 4 * 1024];
  const int t = threadIdx.x, l = t & 63, w = t >> 6;
  const int lr = l & 15, lh = l >> 4;
  // XCD-chunked swizzle (768 % 8 == 0)
  const int raw = blockIdx.x;
  const int bid = (raw & 7) * 96 + (raw >> 3);
  const int q0 = (bid & 31) * 64;
  const int head = (bid >> 5) % Hh;
  const int b = bid / (32 * Hh);
  const size_t base = (size_t)b * Hh + head;
  const short* Qh = Qg + base * Nn * HDd;
  const short* Kh = Kg + base * Nn * HDd;
  const short* Vh = Vtg + base * HDd * Nn;
  const int qw = q0 + w * 16;
  const int PB = 16384 + w * 1024;

  const bf16x8 onesf = {0x3F80, 0x3F80, 0x3F80, 0x3F80,
                        0x3F80, 0x3F80, 0x3F80, 0x3F80};

  int fof[2][4], wofi[4], pof[2];
#pragma unroll
  for (int kp = 0; kp < 2; ++kp) {
#pragma unroll
    for (int i = 0; i < 4; ++i)
      fof[kp][i] = (i * 16 + lr) * 64 + (((kp * 4 + lh) ^ (lr & 7)) << 3);
    pof[kp] = lr * 64 + (((kp * 4 + lh) ^ (lr & 7)) << 3);
  }
#pragma unroll
  for (int i = 0; i < 4; ++i) {
    const int ch = 2 * i + (lh >> 1);
    wofi[i] = lr * 64 + ((ch ^ (lr & 7)) << 3) + (lh & 1) * 4;
  }

  bf16x8 qf[2];
#pragma unroll
  for (int kp = 0; kp < 2; ++kp)
    qf[kp] = *(const bf16x8*)&Qh[(size_t)(qw + lr) * HDd + kp * 32 + lh * 8];

  f32x4 accO[4], accL;
  accL = (f32x4){0.f, 0.f, 0.f, 0.f};
#pragma unroll
  for (int j = 0; j < 4; ++j) accO[j] = (f32x4){0.f, 0.f, 0.f, 0.f};

  auto stageK = [&](const int kb, const int tile) {
    const short* Kt = Kh + (size_t)tile * (64 * HDd);
#pragma unroll
    for (int u = 0; u < 2; ++u) {
      const int cu = u * 4 + w;
      const int du = cu * 64 + l;
      const int row = du >> 3, ch = du & 7, sch = ch ^ (row & 7);
      gl_lds16(Kt + row * 64 + sch * 8, &SM[kb + cu * 512]);
    }
  };
  auto stageV = [&](const int vb, const int tile) {
    const short* Vt = Vh + tile * 64;
#pragma unroll
    for (int u = 0; u < 2; ++u) {
      const int cu = u * 4 + w;
      const int du = cu * 64 + l;
      const int row = du >> 3, ch = du & 7, sch = ch ^ (row & 7);
      gl_lds16(Vt + (size_t)row * Nn + sch * 8, &SM[vb + cu * 512]);
    }
  };

  auto qk = [&](const int kb, f32x4 (&sacc)[4]) {
#pragma unroll
    for (int i = 0; i < 4; ++i) sacc[i] = (f32x4){0.f, 0.f, 0.f, 0.f};
#pragma unroll
    for (int kp = 0; kp < 2; ++kp)
#pragma unroll
      for (int i = 0; i < 4; ++i)
        sacc[i] = __builtin_amdgcn_mfma_f32_16x16x32_bf16(
            lds8(&SM[kb + fof[kp][i]]), qf[kp], sacc[i], 0, 0, 0);
  };
  auto expw = [&](const f32x4 (&sacc)[4]) {
#pragma unroll
    for (int i = 0; i < 4; ++i) {
      const float p0 = exp2f(sacc[i][0]), p1 = exp2f(sacc[i][1]);
      const float p2 = exp2f(sacc[i][2]), p3 = exp2f(sacc[i][3]);
      uint2 pk;
      pk.x = cvtpk(p0, p1);
      pk.y = cvtpk(p2, p3);
      *(uint2*)&SM[PB + wofi[i]] = pk;
    }
  };
  auto pv = [&](const int vb) {
#pragma unroll
    for (int kp = 0; kp < 2; ++kp) {
      const bf16x8 pa = lds8(&SM[PB + pof[kp]]);
      accL = __builtin_amdgcn_mfma_f32_16x16x32_bf16(pa, onesf, accL, 0, 0, 0);
#pragma unroll
      for (int j = 0; j < 4; ++j)
        accO[j] = __builtin_amdgcn_mfma_f32_16x16x32_bf16(
            pa, lds8(&SM[vb + fof[kp][j]]), accO[j], 0, 0, 0);
    }
  };

  f32x4 sA[4], sB[4];
  // prologue
  stageK(0, 0);
  __syncthreads();
  // t = 0
  stageK(4096, 1);
  stageV(8192, 0);
  qk(0, sA);
  __syncthreads();
#pragma unroll 1
  for (int it = 1; it < 31; it += 2) {
    // t = it (odd): K in buf1, exp/PV of t-1 (V even -> Vbuf0)
    stageK(0, it + 1);
    stageV(12288, it);
    qk(4096, sB);
    expw(sA);
    pv(8192);
    __syncthreads();
    // t = it+1 (even)
    stageK(4096, it + 2);
    stageV(8192, it + 1);
    qk(0, sA);
    expw(sB);
    pv(12288);
    __syncthreads();
  }
  // t = 31 (odd): no K(32)
  stageV(12288, 31);
  qk(4096, sB);
  expw(sA);
  pv(8192);
  __syncthreads();
  // finish tile 31
  expw(sB);
  pv(12288);

  f32x4 linvq;
#pragma unroll
  for (int r = 0; r < 4; ++r) linvq[r] = 1.0f / accL[r];
  if (lr == 0) *(f32x4*)&Linv[base * Nn + qw + 4 * lh] = linvq;
#pragma unroll
  for (int j = 0; j < 4; ++j)
#pragma unroll
    for (int r = 0; r < 4; ++r)
      OHb[((size_t)b * Nn + qw + 4 * lh + r) * Cc + head * HDd + j * 16 + lr] =
          f2bf(accO[j][r] * linvq[r]);
}

// ---------------------------------------------------------------------------
// Score: score[b][q][kv] = (1/H) sum_h 2^(qk) * Linv[b,h,q].
// Grid 2048 = (b, 64-q, 64-kv); 4 waves x 16 q.  Phase-shifted over heads:
// body(h) = stage K(h+1) ; prefetch Q(h+1), linv(h) ; QK(h) ; expacc(h-1).
// Output staged in LDS -> contiguous 256B row stores.
// ---------------------------------------------------------------------------
__global__ __launch_bounds__(256, 4) void score_mfma(
    const short* __restrict__ Qg, const short* __restrict__ Kg,
    const float* __restrict__ Linv, float* __restrict__ score) {
  __shared__ __align__(16) char SMraw[64 * 68 * 4];  // 17408 B
  short* SK = (short*)SMraw;   // K dbuf: 2 x 4096 shorts (16 KB)
  float* SMf = (float*)SMraw;  // out staging [64][68] after the loop
  const int t = threadIdx.x, l = t & 63, w = t >> 6;
  const int lr = l & 15, lh = l >> 4;
  // XCD map: xcd -> (b = xcd>>2, 8 q-tiles) x 32 kv-tiles
  const int raw = blockIdx.x;  // 2048
  const int xcd = raw & 7, idx = raw >> 3;
  const int b = xcd >> 2;
  const int q0 = ((xcd & 3) * 8 + (idx >> 5)) * 64;
  const int kv0 = (idx & 31) * 64;
  const int qw = q0 + w * 16;

  int fof[2][4];
#pragma unroll
  for (int kp = 0; kp < 2; ++kp)
#pragma unroll
    for (int i = 0; i < 4; ++i)
      fof[kp][i] = (i * 16 + lr) * 64 + (((kp * 4 + lh) ^ (lr & 7)) << 3);

  f32x4 sc[4];
#pragma unroll
  for (int i = 0; i < 4; ++i) sc[i] = (f32x4){0.f, 0.f, 0.f, 0.f};

  auto stage = [&](const int kb, const int h) {
    const short* Kt = Kg + (((size_t)b * Hh + h) * Nn + kv0) * HDd;
#pragma unroll
    for (int u = 0; u < 2; ++u) {
      const int cu = u * 4 + w;
      const int du = cu * 64 + l;
      const int row = du >> 3, ch = du & 7, sch = ch ^ (row & 7);
      gl_lds16(Kt + row * 64 + sch * 8, &SK[kb + cu * 512]);
    }
  };
  auto ldqQ = [&](const int h, bf16x8& a0, bf16x8& a1) {
    const size_t hb = (size_t)b * Hh + h;
    a0 = *(const bf16x8*)&Qg[(hb * Nn + qw + lr) * HDd + lh * 8];
    a1 = *(const bf16x8*)&Qg[(hb * Nn + qw + lr) * HDd + 32 + lh * 8];
  };
  auto qk = [&](const int kb, const bf16x8 a0, const bf16x8 a1,
                f32x4 (&sacc)[4]) {
#pragma unroll
    for (int i = 0; i < 4; ++i) sacc[i] = (f32x4){0.f, 0.f, 0.f, 0.f};
#pragma unroll
    for (int i = 0; i < 4; ++i)
      sacc[i] = __builtin_amdgcn_mfma_f32_16x16x32_bf16(
          lds8(&SK[kb + fof[0][i]]), a0, sacc[i], 0, 0, 0);
#pragma unroll
    for (int i = 0; i < 4; ++i)
      sacc[i] = __builtin_amdgcn_mfma_f32_16x16x32_bf16(
          lds8(&SK[kb + fof[1][i]]), a1, sacc[i], 0, 0, 0);
  };
  auto expacc = [&](const f32x4 (&sacc)[4], const float lv) {
#pragma unroll
    for (int i = 0; i < 4; ++i)
#pragma unroll
      for (int r = 0; r < 4; ++r) sc[i][r] += exp2f(sacc[i][r]) * lv;
  };

  bf16x8 qA0, qA1, qB0, qB1;
  float lvA, lvB;
  f32x4 sA[4], sB[4];
  // prologue
  stage(0, 0);
  ldqQ(0, qA0, qA1);
  __syncthreads();
  // h = 0
  stage(4096, 1);
  ldqQ(1, qB0, qB1);
  lvA = Linv[((size_t)b * Hh + 0) * Nn + qw + lr];
  qk(0, qA0, qA1, sA);
  __syncthreads();
#pragma unroll 1
  for (int h = 1; h < 11; h += 2) {
    // h odd
    stage(0, h + 1);
    ldqQ(h + 1, qA0, qA1);
    lvB = Linv[((size_t)b * Hh + h) * Nn + qw + lr];
    qk(4096, qB0, qB1, sB);
    expacc(sA, lvA);
    __syncthreads();
    // h+1 even
    stage(4096, h + 2);
    ldqQ(h + 2, qB0, qB1);
    lvA = Linv[((size_t)b * Hh + h + 1) * Nn + qw + lr];
    qk(0, qA0, qA1, sA);
    expacc(sB, lvB);
    __syncthreads();
  }
  // h = 11 (odd): no head 12
  lvB = Linv[((size_t)b * Hh + 11) * Nn + qw + lr];
  qk(4096, qB0, qB1, sB);
  expacc(sA, lvA);
  expacc(sB, lvB);
  __syncthreads();  // all K reads done before LDS reuse

  constexpr float invH = 1.0f / 12.0f;
#pragma unroll
  for (int i = 0; i < 4; ++i) {
    f32x4 o;
#pragma unroll
    for (int r = 0; r < 4; ++r) o[r] = sc[i][r] * invH;
    *(f32x4*)&SMf[(w * 16 + lr) * 68 + i * 16 + 4 * lh] = o;
  }
  __syncthreads();
#pragma unroll
  for (int s = 0; s < 4; ++s) {
    const int lin = t + s * 256;
    const int row = lin >> 4, ch = lin & 15;  // 16 threads = one 256B row
    const f32x4 v = *(const f32x4*)&SMf[row * 68 + ch * 4];
    *(f32x4*)&score[((size_t)b * Nn + q0 + row) * Nn + kv0 + ch * 4] = v;
  }
}

// ---------------------------------------------------------------------------
// Proj GEMM: out[m][c] = sum_k OH[m][k]*pw[c][k] + bias[c]
// ---------------------------------------------------------------------------
__global__ __launch_bounds__(256) void proj_mfma(
    const short* __restrict__ A, const short* __restrict__ W,
    const float* __restrict__ bias, float* __restrict__ out) {
  __shared__ short As[128 * 64];
  __shared__ short Bs[128 * 64];
  const int t = threadIdx.x, l = t & 63, w = t >> 6;
  const int lr = l & 15, lh = l >> 4;
  const int m0 = blockIdx.x * 128, c0 = blockIdx.y * 128;
  const int wr = w >> 1, wc = w & 1;
  f32x4 acc[4][4];
#pragma unroll
  for (int i = 0; i < 4; ++i)
#pragma unroll
    for (int j = 0; j < 4; ++j) acc[i][j] = (f32x4){0.f, 0.f, 0.f, 0.f};

  for (int k0 = 0; k0 < Cc; k0 += 64) {
    __syncthreads();
#pragma unroll
    for (int u = 0; u < 4; ++u) {
      const int du = (w * 4 + u) * 64 + l;
      const int row = du >> 3, ch = du & 7, sch = ch ^ (row & 7);
      gl_lds16(A + (size_t)(m0 + row) * Cc + k0 + sch * 8,
               &As[(w * 4 + u) * 512]);
      gl_lds16(W + (size_t)(c0 + row) * Cc + k0 + sch * 8,
               &Bs[(w * 4 + u) * 512]);
    }
    __syncthreads();
#pragma unroll
    for (int kp = 0; kp < 2; ++kp) {
      bf16x8 af[4], bfv[4];
#pragma unroll
      for (int i = 0; i < 4; ++i)
        af[i] = ld_frag(As, wr * 64 + i * 16 + lr, kp * 4 + lh);
#pragma unroll
      for (int j = 0; j < 4; ++j)
        bfv[j] = ld_frag(Bs, wc * 64 + j * 16 + lr, kp * 4 + lh);
#pragma unroll
      for (int i = 0; i < 4; ++i)
#pragma unroll
        for (int j = 0; j < 4; ++j)
          acc[i][j] = __builtin_amdgcn_mfma_f32_16x16x32_bf16(
              af[i], bfv[j], acc[i][j], 0, 0, 0);
    }
  }
#pragma unroll
  for (int j = 0; j < 4; ++j) {
    const int c = c0 + wc * 64 + j * 16 + lr;
    const float bi = bias[c];
#pragma unroll
    for (int i = 0; i < 4; ++i)
#pragma unroll
      for (int r = 0; r < 4; ++r) {
        const int m = m0 + wr * 64 + i * 16 + lh * 4 + r;
        out[(size_t)m * Cc + c] = acc[i][j][r] + bi;
      }
  }
}

// ---------------------------------------------------------------------------
extern "C" void kernel_launch(void* const* d_in, const int* in_sizes, int n_in,
                              void* d_out, int out_size, void* d_ws,
                              size_t ws_size, hipStream_t stream) {
  const float* x = (const float*)d_in[0];
  const float* qkv_w = (const float*)d_in[1];
  const float* proj_w = (const float*)d_in[2];
  const float* proj_b = (const float*)d_in[3];

  float* out = (float*)d_out;
  float* score = out + (size_t)Bb * Nn * Cc;

  const size_t nx = (size_t)Bb * Nn * Cc;
  const size_t nwq = (size_t)3 * Cc * Cc;
  const size_t npw = (size_t)Cc * Cc;
  short* xb = (short*)d_ws;
  short* wqb = xb + nx;
  short* pwb = wqb + nwq;
  short* Qb = pwb + npw;
  short* Kb = Qb + nx;
  short* Vtb = Kb + nx;
  short* OHb = Vtb + nx;
  float* Linv = (float*)(OHb + nx);

  cvt_kernel<<<dim3((int)(nx / 1024)), 256, 0, stream>>>(x, xb);
  cvt_kernel<<<dim3((int)(nwq / 1024)), 256, 0, stream>>>(qkv_w, wqb);
  cvt_kernel<<<dim3((int)(npw / 1024)), 256, 0, stream>>>(proj_w, pwb);
  qkv_mfma<<<dim3(32, 18), 256, 0, stream>>>(xb, wqb, Qb, Kb, Vtb);
  attn_pass1<<<dim3(768), 256, 0, stream>>>(Qb, Kb, Vtb, Linv, OHb);
  score_mfma<<<dim3(2048), 256, 0, stream>>>(Qb, Kb, Linv, score);
  proj_mfma<<<dim3(32, 6), 256, 0, stream>>>(OHb, pwb, proj_b, out);
}